// Round 13
// baseline (1264.380 us; speedup 1.0000x reference)
//
#include <hip/hip_runtime.h>
#include <cstdint>
#include <cstddef>

#define SLEN 1024
#define BATCH 64
#define EDIM 256
#define HDIM 128   // hidden per direction
#define GDIM 512   // 4*HDIM
#define NTAG 4
#define VOCAB 32000

typedef float f2 __attribute__((ext_vector_type(2)));
typedef float f4 __attribute__((ext_vector_type(4)));

// ---------------------------------------------------------------------------
// ws layout (table path), floats:
//   T : [32000][1024]  gate-input table  embed@W_ih_cat^T + (b_ih+b_hh)
//   H : [S][B][256]
//   F : [S][B][4]
// Fallback (old pipelined path) if ws too small: Z0|Z1|H|F|ST as before.
//
// SESSION LEDGER: per-step cost of the 256KB W_hh delivery per LSTM CU:
//   R4  scratch-spill (lstm_k below)  0.72 us/step   <- BEST (compiler-
//       scheduled reload; ~45 TB/s aggregate, above documented L2 ceilings)
//   R9  explicit L2 stream 0.82 | R7 1024thr+fence 0.87 | R5 1024thr 0.88
//   R10 half-W in LDS 0.94 (LDS issue ~= its data) | R8 B_b=2 1.32
// VGPR residency allocator-blocked (0-for-5). LSTM floor ~737us stands.
// R12: attack table_k instead (was 360us = 30% fp32 peak, LDS-issue-bound):
// lane=row / wave=16-cols makes W wave-uniform -> s_load + SGPR-operand
// v_fmac; B leaves the LDS pipe entirely.
// ---------------------------------------------------------------------------

__device__ __forceinline__ float sigm_f(float x) {
    return 1.0f / (1.0f + __expf(-x));
}
__device__ __forceinline__ float tanh_f(float x) {
    return 1.0f - 2.0f / (1.0f + __expf(2.0f * x));
}

template <int CTRL>
__device__ __forceinline__ float quad_perm(float x) {
    return __int_as_float(
        __builtin_amdgcn_mov_dpp(__float_as_int(x), CTRL, 0xF, 0xF, true));
}
#define QP_XOR1 0xB1    // quad_perm [1,0,3,2]
#define QP_XOR2 0x4E    // quad_perm [2,3,0,1]
#define QP_MIR8 0x141   // row_half_mirror: lane p <-> 7-p within each 8
#define QP_BC0  0x00    // quad broadcast lane 0
#define QP_BC1  0x55
#define QP_BC2  0xAA
#define QP_BC3  0xFF

// ---------------------------------------------------------------------------
// table_k v2 (scalar-operand GEMM):
//   grid (500, 8), 512 threads. Block = 64 vocab rows x 128 cols.
//   lane (t&63) = row-in-tile; wave w = t>>6 (readfirstlane -> SGPR) owns
//   cols [bid.y*128 + w*16, +16). W[c][k0..k0+16) is contiguous row-major
//   and wave-uniform -> s_load; inner fmac reads the weight as an SGPR.
//   A staged per-kt in 5KB LDS (pad 20 -> 2-way max on b128 reads = free).
//   32000 = 500*64 exactly: no row tail.
// ---------------------------------------------------------------------------
__global__ __launch_bounds__(512) void table_k(
    const float* __restrict__ embed,
    const float* __restrict__ w_ih_f, const float* __restrict__ w_ih_r,
    const float* __restrict__ b_ih_f, const float* __restrict__ b_hh_f,
    const float* __restrict__ b_ih_r, const float* __restrict__ b_hh_r,
    float* __restrict__ T)
{
    __shared__ __align__(16) float As[64 * 20];   // 5 KB

    const int t    = threadIdx.x;
    const int lane = t & 63;
    const int w    = __builtin_amdgcn_readfirstlane(t >> 6);   // 0..7, SGPR
    const int rowbase = blockIdx.x * 64;
    const int row  = rowbase + lane;
    const int gcol = blockIdx.y * 128 + w * 16;   // 0..1023, wave-uniform
    const int dir  = gcol >> 9;
    const int c0   = gcol & 511;

    const float* Wd = dir ? w_ih_r : w_ih_f;
    const float* bi = dir ? b_ih_r : b_ih_f;
    const float* bh = dir ? b_hh_r : b_hh_f;

    float acc[16];
    #pragma unroll
    for (int c = 0; c < 16; ++c) acc[c] = 0.0f;

    for (int kt = 0; kt < 16; ++kt) {
        const int k0 = kt * 16;
        __syncthreads();
        if (t < 256) {
            const int r = t >> 2, e = t & 3;
            const float4 v = *(const float4*)(
                embed + (size_t)(rowbase + r) * EDIM + k0 + e * 4);
            *(float4*)(As + r * 20 + e * 4) = v;
        }
        __syncthreads();

        const f4 a0 = *(const f4*)(As + lane * 20);
        const f4 a1 = *(const f4*)(As + lane * 20 + 4);
        const f4 a2 = *(const f4*)(As + lane * 20 + 8);
        const f4 a3 = *(const f4*)(As + lane * 20 + 12);
        const float ar[16] = {a0.x, a0.y, a0.z, a0.w,
                              a1.x, a1.y, a1.z, a1.w,
                              a2.x, a2.y, a2.z, a2.w,
                              a3.x, a3.y, a3.z, a3.w};

        #pragma unroll
        for (int c = 0; c < 16; ++c) {
            const float* wr = Wd + (size_t)(c0 + c) * EDIM + k0;  // uniform
            #pragma unroll
            for (int k = 0; k < 16; ++k)
                acc[c] = fmaf(wr[k], ar[k], acc[c]);   // v_fmac v,s,v
        }
    }

    #pragma unroll
    for (int c = 0; c < 16; ++c) acc[c] += bi[c0 + c] + bh[c0 + c];

    float* tp = T + (size_t)row * 1024 + gcol;
    #pragma unroll
    for (int j = 0; j < 4; ++j) {
        f4 o;
        o.x = acc[j * 4 + 0]; o.y = acc[j * 4 + 1];
        o.z = acc[j * 4 + 2]; o.w = acc[j * 4 + 3];
        *(f4*)(tp + j * 4) = o;
    }
}

// ---------------------------------------------------------------------------
// lstm_k (R4/v12 exact): one block per (b,dir), 512 threads, full sequence.
// Compiler-scheduled scratch reload of w2 is the fastest measured W-delivery
// (0.72 us/step, ledger above). Do not "improve" without beating 737 us.
// ---------------------------------------------------------------------------
__global__ __launch_bounds__(512) __attribute__((amdgpu_waves_per_eu(2, 2)))
void lstm_k(
    const float* __restrict__ T, const int* __restrict__ sent,
    const float* __restrict__ w_hh_f, const float* __restrict__ w_hh_r,
    float* __restrict__ H)
{
    __shared__ __align__(16) float sh_h[320];   // [2][160] padded 32->36
    __shared__ int sh_tok[SLEN];

    const int bid = blockIdx.x;
    const int b   = bid & 63;
    const int dir = bid >> 6;
    const int q   = threadIdx.x;     // 0..511
    const int p   = q & 7;
    const int Q   = q >> 3;          // 0..63
    const int gt  = p & 3;           // gate i,f,g,o
    const int hi  = p >> 2;          // 0: unit Q, 1: unit Q+64
    const int u   = Q + hi * 64;

    const float* Whh = dir ? w_hh_r : w_hh_f;

    f2 w2[8][8];
    #pragma unroll
    for (int pr = 0; pr < 8; ++pr) {
        const int uu = (pr & 4) ? (Q + 64) : Q;
        const int gg = pr & 3;
        const f2* src =
            (const f2*)(Whh + ((size_t)(gg * 128 + uu) * 128 + p * 16));
        #pragma unroll
        for (int i = 0; i < 8; ++i) w2[pr][i] = src[i];
    }
    #pragma unroll
    for (int pr = 0; pr < 8; ++pr)
        #pragma unroll
        for (int i = 0; i < 8; ++i)
            asm volatile("" : "+v"(w2[pr][i]));

    sh_tok[q]       = sent[b * SLEN + q];
    sh_tok[512 + q] = sent[b * SLEN + 512 + q];
    if (q < 128) sh_h[(q >> 5) * 36 + (q & 31)] = 0.0f;
    float c = 0.0f;
    __syncthreads();

    const int zcol = dir * 512 + gt * 128 + u;
    const ptrdiff_t hstride = dir ? -16384 : 16384;
    float* hg = H + ((size_t)(dir ? (SLEN - 1) : 0) * 64 + b) * 256
              + dir * 128 + u;

    const bool k4 = (p & 4) != 0;
    const bool k2 = (p & 2) != 0;
    const bool k1 = (p & 1) != 0;
    const float gsc  = (gt == 2) ? 2.0f : 1.0f;    // tanh(x)=2*sigm(2x)-1
    const float gofs = (gt == 2) ? -1.0f : 0.0f;
    const int shr = (p >> 1) * 36 + (p & 1) * 16;
    const int shw = (u >> 5) * 36 + (u & 31);

    float zcur[4], znxt[4];
    #pragma unroll
    for (int dt = 0; dt < 4; ++dt) {
        const int s = dir ? (SLEN - 1 - dt) : dt;
        zcur[dt] = T[((size_t)sh_tok[s] << 10) + zcol];
    }

    for (int t0 = 0; t0 < SLEN; t0 += 4) {
        const bool more = (t0 + 4 < SLEN);
        if (more) {
            #pragma unroll
            for (int dt = 0; dt < 4; ++dt) {
                const int tn = t0 + 4 + dt;
                const int s = dir ? (SLEN - 1 - tn) : tn;
                znxt[dt] = T[((size_t)sh_tok[s] << 10) + zcol];
            }
        }

        #pragma unroll
        for (int dt = 0; dt < 4; ++dt) {
            const f4* hp = (const f4*)(sh_h + (dt & 1) * 160 + shr);
            f2 hv[8];
            #pragma unroll
            for (int i = 0; i < 4; ++i) {
                f4 v = hp[i];
                hv[2 * i]     = __builtin_shufflevector(v, v, 0, 1);
                hv[2 * i + 1] = __builtin_shufflevector(v, v, 2, 3);
            }
            float s[8];
            #pragma unroll
            for (int pr = 0; pr < 8; ++pr) {
                f2 a = (f2)(0.0f);
                #pragma unroll
                for (int i = 0; i < 8; ++i) a += w2[pr][i] * hv[i];
                s[pr] = a.x + a.y;
            }
            float K1[4];
            #pragma unroll
            for (int j = 0; j < 4; ++j) {
                float keep = k4 ? s[j + 4] : s[j];
                float send = k4 ? s[j] : s[j + 4];
                K1[j] = keep + quad_perm<QP_MIR8>(send);
            }
            float K2[2];
            #pragma unroll
            for (int j = 0; j < 2; ++j) {
                float keep = k2 ? K1[j + 2] : K1[j];
                float send = k2 ? K1[j] : K1[j + 2];
                K2[j] = keep + quad_perm<QP_XOR2>(send);
            }
            float keep3 = k1 ? K2[1] : K2[0];
            float send3 = k1 ? K2[0] : K2[1];
            float zv = keep3 + quad_perm<QP_XOR1>(send3) + zcur[dt];

            float sgv = sigm_f(zv * gsc);
            float act = fmaf(sgv, gsc, gofs);

            float a_i = quad_perm<QP_BC0>(act);
            float a_f = quad_perm<QP_BC1>(act);
            float a_g = quad_perm<QP_BC2>(act);
            float a_o = quad_perm<QP_BC3>(act);
            c = a_f * c + a_i * a_g;
            float h = a_o * tanh_f(c);

            if (gt == 0) {                  // p==0 writes unit Q, p==4 -> Q+64
                sh_h[((dt + 1) & 1) * 160 + shw] = h;
                *hg = h;
            }
            hg += hstride;
            __syncthreads();
        }

        if (more) {
            #pragma unroll
            for (int dt = 0; dt < 4; ++dt) zcur[dt] = znxt[dt];
        }
    }
}

// ===========================================================================
// FALLBACK path kernels (old pipelined design), used only if ws too small.
// ===========================================================================
__device__ __forceinline__ void gemm_body(
    float* smem, int mt, int cp,
    const int* __restrict__ sent, const float* __restrict__ embed,
    const float* __restrict__ w_ih_f, const float* __restrict__ w_ih_r,
    const float* __restrict__ b_ih_f, const float* __restrict__ b_hh_f,
    const float* __restrict__ b_ih_r, const float* __restrict__ b_hh_r,
    float* __restrict__ Z, int base_f, int base_r)
{
    float* As = smem;
    const int t  = threadIdx.x;
    const int tm = t >> 8;
    const int tt = t & 255;
    float* Bs = smem + 4096 + tm * 4096;

    const int nt  = cp * 2 + tm;
    const int dir = nt >> 2;
    const float* W  = dir ? w_ih_r : w_ih_f;
    const float* bi = dir ? b_ih_r : b_ih_f;
    const float* bh = dir ? b_hh_r : b_hh_f;
    const int ncol = (nt & 3) * 128;
    const int r0   = mt * 128;

    const int sra = t & 127;
    const int qa  = t >> 7;
    const int r_loc = r0 + sra;
    const int s_loc = r_loc >> 6;
    const int b_    = r_loc & 63;
    const int s_glob = (dir ? base_r : base_f) + s_loc;
    const int tok = sent[b_ * SLEN + s_glob];
    const float* arow = embed + (size_t)tok * EDIM + qa * 8;

    const int srb = tt & 127;
    const int hb  = tt >> 7;
    const float* brow = W + (size_t)(ncol + srb) * EDIM + hb * 16;

    const int tx = tt & 15, ty = tt >> 4;

    f2 acc[8][4];
    #pragma unroll
    for (int i = 0; i < 8; ++i)
        #pragma unroll
        for (int jj = 0; jj < 4; ++jj) acc[i][jj] = (f2)(0.0f);

    for (int kt = 0; kt < 8; ++kt) {
        const int k0 = kt * 32;
        __syncthreads();
        {
            float4 v0 = *(const float4*)(arow + k0);
            float4 v1 = *(const float4*)(arow + k0 + 4);
            const int kk = qa * 8;
            As[(kk + 0) * 128 + sra] = v0.x;
            As[(kk + 1) * 128 + sra] = v0.y;
            As[(kk + 2) * 128 + sra] = v0.z;
            As[(kk + 3) * 128 + sra] = v0.w;
            As[(kk + 4) * 128 + sra] = v1.x;
            As[(kk + 5) * 128 + sra] = v1.y;
            As[(kk + 6) * 128 + sra] = v1.z;
            As[(kk + 7) * 128 + sra] = v1.w;
        }
        #pragma unroll
        for (int i = 0; i < 4; ++i) {
            float4 v = *(const float4*)(brow + k0 + i * 4);
            const int kk = hb * 16 + i * 4;
            Bs[(kk + 0) * 128 + srb] = v.x;
            Bs[(kk + 1) * 128 + srb] = v.y;
            Bs[(kk + 2) * 128 + srb] = v.z;
            Bs[(kk + 3) * 128 + srb] = v.w;
        }
        __syncthreads();

        #pragma unroll 8
        for (int k = 0; k < 32; ++k) {
            const f4 a0  = *(const f4*)&As[k * 128 + ty * 4];
            const f4 a1  = *(const f4*)&As[k * 128 + 64 + ty * 4];
            const f4 bq0 = *(const f4*)&Bs[k * 128 + tx * 4];
            const f4 bq1 = *(const f4*)&Bs[k * 128 + 64 + tx * 4];
            float av[8] = {a0.x, a0.y, a0.z, a0.w, a1.x, a1.y, a1.z, a1.w};
            f2 bv[4];
            bv[0] = __builtin_shufflevector(bq0, bq0, 0, 1);
            bv[1] = __builtin_shufflevector(bq0, bq0, 2, 3);
            bv[2] = __builtin_shufflevector(bq1, bq1, 0, 1);
            bv[3] = __builtin_shufflevector(bq1, bq1, 2, 3);
            #pragma unroll
            for (int i = 0; i < 8; ++i) {
                f2 as; as.x = av[i]; as.y = av[i];
                #pragma unroll
                for (int jj = 0; jj < 4; ++jj)
                    acc[i][jj] += as * bv[jj];
            }
        }
    }

    float bias0[4], bias1[4];
    #pragma unroll
    for (int j = 0; j < 4; ++j) {
        bias0[j] = bi[ncol + tx * 4 + j] + bh[ncol + tx * 4 + j];
        bias1[j] = bi[ncol + 64 + tx * 4 + j] + bh[ncol + 64 + tx * 4 + j];
    }

    #pragma unroll
    for (int i = 0; i < 8; ++i) {
        const int row = r0 + ((i < 4) ? (ty * 4 + i) : (64 + ty * 4 + i - 4));
        float* zp = Z + (size_t)row * 1024 + dir * 512 + ncol;
        float4 o0, o1;
        o0.x = acc[i][0].x + bias0[0]; o0.y = acc[i][0].y + bias0[1];
        o0.z = acc[i][1].x + bias0[2]; o0.w = acc[i][1].y + bias0[3];
        o1.x = acc[i][2].x + bias1[0]; o1.y = acc[i][2].y + bias1[1];
        o1.z = acc[i][3].x + bias1[2]; o1.w = acc[i][3].y + bias1[3];
        *(float4*)(zp + tx * 4)      = o0;
        *(float4*)(zp + 64 + tx * 4) = o1;
    }
}

__device__ __forceinline__ void lstm_body(
    float* smem,
    const float* __restrict__ Z, const float* __restrict__ w_hh_f,
    const float* __restrict__ w_hh_r, float* __restrict__ H,
    float* __restrict__ ST, int base_f, int base_r, int L, int first)
{
    float* sh_h = smem;

    const int bid = blockIdx.x;
    const int b   = bid & 63;
    const int dir = bid >> 6;
    const int q   = threadIdx.x;
    const int p   = q & 7;
    const int Q   = q >> 3;
    const int gt  = p & 3;
    const int hi  = p >> 2;
    const int u   = Q + hi * 64;

    const float* Whh = dir ? w_hh_r : w_hh_f;

    f2 w2[8][8];
    #pragma unroll
    for (int pr = 0; pr < 8; ++pr) {
        const int uu = (pr & 4) ? (Q + 64) : Q;
        const int gg = pr & 3;
        const f2* src =
            (const f2*)(Whh + ((size_t)(gg * 128 + uu) * 128 + p * 16));
        #pragma unroll
        for (int i = 0; i < 8; ++i) w2[pr][i] = src[i];
    }

    float* stp = ST + (size_t)(dir * 64 + b) * 256;
    if (q < 128)
        sh_h[(q >> 5) * 36 + (q & 31)] = first ? 0.0f : stp[q];
    float c = first ? 0.0f : stp[128 + u];

    const ptrdiff_t zstride = dir ? -65536 : 65536;
    const float* zp0 = Z + (size_t)b * 1024 + dir * 512
                     + (dir ? (size_t)(L - 1) * 65536 : 0) + gt * 128 + u;
    const ptrdiff_t hstride = dir ? -16384 : 16384;
    float* hg = H + ((size_t)(dir ? (base_r + L - 1) : base_f) * 64 + b) * 256
              + dir * 128 + u;

    const bool k4 = (p & 4) != 0;
    const bool k2 = (p & 2) != 0;
    const bool k1 = (p & 1) != 0;
    const float gsc  = (gt == 2) ? 2.0f : 1.0f;
    const float gofs = (gt == 2) ? -1.0f : 0.0f;
    const int shr = (p >> 1) * 36 + (p & 1) * 16;
    const int shw = (u >> 5) * 36 + (u & 31);

    float zcur[4], znxt[4];
    {
        const float* zp = zp0;
        #pragma unroll
        for (int dt = 0; dt < 4; ++dt) { zcur[dt] = *zp; zp += zstride; }
    }
    __syncthreads();

    float hlast = 0.0f;

    for (int t0 = 0; t0 < L; t0 += 4) {
        const bool more = (t0 + 4 < L);
        if (more) {
            const float* zp = zp0 + (ptrdiff_t)(t0 + 4) * zstride;
            #pragma unroll
            for (int dt = 0; dt < 4; ++dt) { znxt[dt] = *zp; zp += zstride; }
        }

        #pragma unroll
        for (int dt = 0; dt < 4; ++dt) {
            const f4* hp = (const f4*)(sh_h + (dt & 1) * 160 + shr);
            f2 hv[8];
            #pragma unroll
            for (int i = 0; i < 4; ++i) {
                f4 v = hp[i];
                hv[2 * i]     = __builtin_shufflevector(v, v, 0, 1);
                hv[2 * i + 1] = __builtin_shufflevector(v, v, 2, 3);
            }
            float s[8];
            #pragma unroll
            for (int pr = 0; pr < 8; ++pr) {
                f2 a = (f2)(0.0f);
                #pragma unroll
                for (int i = 0; i < 8; ++i) a += w2[pr][i] * hv[i];
                s[pr] = a.x + a.y;
            }
            float K1[4];
            #pragma unroll
            for (int j = 0; j < 4; ++j) {
                float keep = k4 ? s[j + 4] : s[j];
                float send = k4 ? s[j] : s[j + 4];
                K1[j] = keep + quad_perm<QP_MIR8>(send);
            }
            float K2[2];
            #pragma unroll
            for (int j = 0; j < 2; ++j) {
                float keep = k2 ? K1[j + 2] : K1[j];
                float send = k2 ? K1[j] : K1[j + 2];
                K2[j] = keep + quad_perm<QP_XOR2>(send);
            }
            float keep3 = k1 ? K2[1] : K2[0];
            float send3 = k1 ? K2[0] : K2[1];
            float zv = keep3 + quad_perm<QP_XOR1>(send3) + zcur[dt];

            float sgv = sigm_f(zv * gsc);
            float act = fmaf(sgv, gsc, gofs);

            float a_i = quad_perm<QP_BC0>(act);
            float a_f = quad_perm<QP_BC1>(act);
            float a_g = quad_perm<QP_BC2>(act);
            float a_o = quad_perm<QP_BC3>(act);
            c = a_f * c + a_i * a_g;
            float h = a_o * tanh_f(c);
            hlast = h;

            if (gt == 0) {
                sh_h[((dt + 1) & 1) * 160 + shw] = h;
                *hg = h;
            }
            hg += hstride;
            __syncthreads();
        }

        if (more) {
            #pragma unroll
            for (int dt = 0; dt < 4; ++dt) zcur[dt] = znxt[dt];
        }
    }

    if (gt == 0) {
        stp[u] = hlast;
        stp[128 + u] = c;
    }
}

__global__ __launch_bounds__(512) void fused_lstm_gemm(
    const int* __restrict__ sent, const float* __restrict__ embed,
    const float* __restrict__ w_ih_f, const float* __restrict__ w_ih_r,
    const float* __restrict__ b_ih_f, const float* __restrict__ b_hh_f,
    const float* __restrict__ b_ih_r, const float* __restrict__ b_hh_r,
    float* __restrict__ Zw, int gbase_f, int gbase_r, int mtiles,
    const float* __restrict__ Zr, const float* __restrict__ w_hh_f,
    const float* __restrict__ w_hh_r, float* __restrict__ H,
    float* __restrict__ ST, int lbase_f, int lbase_r, int L, int first)
{
    __shared__ __align__(16) float smem[12288];

    if (blockIdx.x < 128) {
        lstm_body(smem, Zr, w_hh_f, w_hh_r, H, ST, lbase_f, lbase_r, L, first);
    } else {
        const int g  = blockIdx.x - 128;
        const int mt = g % mtiles;
        const int cp = g / mtiles;
        gemm_body(smem, mt, cp, sent, embed, w_ih_f, w_ih_r,
                  b_ih_f, b_hh_f, b_ih_r, b_hh_r, Zw, gbase_f, gbase_r);
    }
}

__global__ __launch_bounds__(512) void gemm_zin(
    const int* __restrict__ sent, const float* __restrict__ embed,
    const float* __restrict__ w_ih_f, const float* __restrict__ w_ih_r,
    const float* __restrict__ b_ih_f, const float* __restrict__ b_hh_f,
    const float* __restrict__ b_ih_r, const float* __restrict__ b_hh_r,
    float* __restrict__ Z, int base_f, int base_r)
{
    __shared__ __align__(16) float smem[12288];
    gemm_body(smem, blockIdx.x, blockIdx.y, sent, embed, w_ih_f, w_ih_r,
              b_ih_f, b_hh_f, b_ih_r, b_hh_r, Z, base_f, base_r);
}

// ---------------------------------------------------------------------------
// Kernel 3: emissions  F[r][t] = H[r] . w_out[t] + b_out[t]
// ---------------------------------------------------------------------------
__global__ __launch_bounds__(256) void emissions_k(
    const float* __restrict__ H, const float* __restrict__ w_out,
    const float* __restrict__ b_out, float* __restrict__ F)
{
    const int gid = blockIdx.x * 256 + threadIdx.x;
    const int r   = gid >> 2;
    const int tg  = gid & 3;
    const float4* h4 = (const float4*)(H + (size_t)r * 256);
    const float4* w4 = (const float4*)(w_out + (size_t)tg * 256);
    float a0 = 0.f, a1 = 0.f, a2 = 0.f, a3 = 0.f;
    #pragma unroll 8
    for (int k = 0; k < 64; ++k) {
        float4 h = h4[k], w = w4[k];
        a0 = fmaf(h.x, w.x, a0); a1 = fmaf(h.y, w.y, a1);
        a2 = fmaf(h.z, w.z, a2); a3 = fmaf(h.w, w.w, a3);
    }
    F[gid] = ((a0 + a1) + (a2 + a3)) + b_out[tg];
}

// ---------------------------------------------------------------------------
// Kernel 4: Viterbi. One block (1 wave) per batch.
// ---------------------------------------------------------------------------
__device__ __forceinline__ unsigned compose_map(unsigned a, unsigned b) {
    unsigned r = 0;
    #pragma unroll
    for (int jj = 0; jj < 4; ++jj) {
        unsigned bj = (b >> (jj * 8)) & 3u;
        unsigned aj = (a >> (bj * 8)) & 3u;
        r |= aj << (jj * 8);
    }
    return r;
}

__global__ __launch_bounds__(64) void viterbi_k(
    const float* __restrict__ F, const float* __restrict__ start_t,
    const float* __restrict__ end_t, const float* __restrict__ trans,
    int* __restrict__ out)
{
    const int b    = blockIdx.x;
    const int lane = threadIdx.x;
    __shared__ __align__(16) float sfeat[SLEN][NTAG];
    __shared__ unsigned sbp[SLEN];

    #pragma unroll
    for (int i = 0; i < 16; ++i) {
        int s = i * 64 + lane;
        ((float4*)sfeat)[s] = *(const float4*)(F + ((size_t)s * BATCH + b) * NTAG);
    }
    __syncthreads();

    const int cur = lane & 3;
    float tr0 = trans[0 * 4 + cur], tr1 = trans[1 * 4 + cur];
    float tr2 = trans[2 * 4 + cur], tr3 = trans[3 * 4 + cur];
    float sc = start_t[cur] + sfeat[0][cur];

    for (int s = 1; s < SLEN; ++s) {
        float ft = sfeat[s][cur];
        float s0 = __shfl(sc, 0), s1 = __shfl(sc, 1);
        float s2 = __shfl(sc, 2), s3 = __shfl(sc, 3);
        float c0 = s0 + tr0, c1 = s1 + tr1, c2 = s2 + tr2, c3 = s3 + tr3;
        float best = c0; int arg = 0;
        if (c1 > best) { best = c1; arg = 1; }
        if (c2 > best) { best = c2; arg = 2; }
        if (c3 > best) { best = c3; arg = 3; }
        sc = best + ft;
        unsigned bp = (unsigned)arg;
        unsigned b0 = __shfl(bp, 0), b1 = __shfl(bp, 1);
        unsigned b2 = __shfl(bp, 2), b3 = __shfl(bp, 3);
        if (lane == 0) sbp[s] = b0 | (b1 << 8) | (b2 << 16) | (b3 << 24);
    }
    sc += end_t[cur];
    float f0 = __shfl(sc, 0), f1 = __shfl(sc, 1);
    float f2v = __shfl(sc, 2), f3 = __shfl(sc, 3);
    int last = 0; float bb = f0;
    if (f1 > bb)  { bb = f1;  last = 1; }
    if (f2v > bb) { bb = f2v; last = 2; }
    if (f3 > bb)  { bb = f3;  last = 3; }
    __syncthreads();

    unsigned m[16];
    #pragma unroll
    for (int k = 0; k < 16; ++k) {
        int s = lane * 16 + k;
        m[k] = (s >= 1) ? sbp[s] : 0x03020100u;
    }
    unsigned G = m[15];
    #pragma unroll
    for (int k = 14; k >= 0; --k) G = compose_map(m[k], G);
    unsigned R = G;
    #pragma unroll
    for (int d = 1; d < 64; d <<= 1) {
        unsigned oo = __shfl_down(R, d);
        if (lane + d < 64) R = compose_map(R, oo);
    }
    unsigned P = __shfl_down(R, 1);
    if (lane == 63) P = 0x03020100u;

    int tcur = (int)((P >> (last * 8)) & 3u);
    int* ob = out + b * SLEN + lane * 16;
    ob[15] = tcur;
    #pragma unroll
    for (int k = 15; k >= 1; --k) {
        tcur = (int)((m[k] >> (tcur * 8)) & 3u);
        ob[k - 1] = tcur;
    }
}

// ---------------------------------------------------------------------------
extern "C" void kernel_launch(void* const* d_in, const int* in_sizes, int n_in,
                              void* d_out, int out_size, void* d_ws, size_t ws_size,
                              hipStream_t stream)
{
    const int*   sent    = (const int*)d_in[0];
    const float* embed   = (const float*)d_in[1];
    const float* w_ih_f  = (const float*)d_in[2];
    const float* w_hh_f  = (const float*)d_in[3];
    const float* b_ih_f  = (const float*)d_in[4];
    const float* b_hh_f  = (const float*)d_in[5];
    const float* w_ih_r  = (const float*)d_in[6];
    const float* w_hh_r  = (const float*)d_in[7];
    const float* b_ih_r  = (const float*)d_in[8];
    const float* b_hh_r  = (const float*)d_in[9];
    const float* w_out   = (const float*)d_in[10];
    const float* b_out   = (const float*)d_in[11];
    const float* start_t = (const float*)d_in[12];
    const float* end_t   = (const float*)d_in[13];
    const float* trans   = (const float*)d_in[14];
    int* out = (int*)d_out;

    const size_t H_FLOATS  = (size_t)SLEN * BATCH * 256;   // 16777216
    const size_t F_FLOATS  = (size_t)SLEN * BATCH * NTAG;  //   262144
    const size_t T_FLOATS  = (size_t)VOCAB * 1024;         // 32768000
    const size_t ST_FLOATS = (size_t)2 * BATCH * 256;

    const size_t table_need = (T_FLOATS + H_FLOATS + F_FLOATS) * sizeof(float);

    if (ws_size >= table_need) {
        // -------- table path --------
        float* T = (float*)d_ws;
        float* H = T + T_FLOATS;
        float* F = H + H_FLOATS;

        table_k<<<dim3(500, 8), 512, 0, stream>>>(
            embed, w_ih_f, w_ih_r, b_ih_f, b_hh_f, b_ih_r, b_hh_r, T);
        lstm_k<<<128, 512, 0, stream>>>(T, sent, w_hh_f, w_hh_r, H);
        emissions_k<<<1024, 256, 0, stream>>>(H, w_out, b_out, F);
        viterbi_k<<<64, 64, 0, stream>>>(F, start_t, end_t, trans, out);
        return;
    }

    // -------- fallback: old pipelined path --------
    const size_t FIXED = H_FLOATS + F_FLOATS + ST_FLOATS;
    int L = 0;
    for (int cand = 256; cand >= 32; cand >>= 1) {
        size_t need = ((size_t)2 * cand * BATCH * 1024 + FIXED) * sizeof(float);
        if (need <= ws_size) { L = cand; break; }
    }

    if (L > 0) {
        const int nch = SLEN / L;
        const int mtiles = (L * BATCH) / 128;
        float* Z0 = (float*)d_ws;
        float* Z1 = Z0 + (size_t)L * BATCH * 1024;
        float* H  = Z1 + (size_t)L * BATCH * 1024;
        float* F  = H + H_FLOATS;
        float* ST = F + F_FLOATS;
        float* Zb[2] = {Z0, Z1};

        gemm_zin<<<dim3(mtiles, 4), 512, 0, stream>>>(
            sent, embed, w_ih_f, w_ih_r, b_ih_f, b_hh_f, b_ih_r, b_hh_r,
            Zb[0], 0, SLEN - L);

        for (int c = 0; c < nch; ++c) {
            const int lbase_f = c * L;
            const int lbase_r = SLEN - (c + 1) * L;
            const int hasg = (c + 1 < nch);
            const int gbase_f = (c + 1) * L;
            const int gbase_r = SLEN - (c + 2) * L;
            const int grid = hasg ? (128 + mtiles * 4) : 128;
            fused_lstm_gemm<<<grid, 512, 0, stream>>>(
                sent, embed, w_ih_f, w_ih_r, b_ih_f, b_hh_f, b_ih_r, b_hh_r,
                Zb[(c + 1) & 1], hasg ? gbase_f : 0, hasg ? gbase_r : 0, mtiles,
                Zb[c & 1], w_hh_f, w_hh_r, H, ST, lbase_f, lbase_r, L,
                c == 0 ? 1 : 0);
        }

        emissions_k<<<1024, 256, 0, stream>>>(H, w_out, b_out, F);
        viterbi_k<<<64, 64, 0, stream>>>(F, start_t, end_t, trans, out);
    } else {
        int Ls = SLEN;
        while (Ls > 32) {
            size_t need = ((size_t)Ls * BATCH * 1024 + FIXED) * sizeof(float);
            if (need <= ws_size) break;
            Ls >>= 1;
        }
        const int nch = SLEN / Ls;
        const int mtiles = (Ls * BATCH) / 128;
        float* Z  = (float*)d_ws;
        float* H  = Z + (size_t)Ls * BATCH * 1024;
        float* F  = H + H_FLOATS;
        float* ST = F + F_FLOATS;

        for (int c = 0; c < nch; ++c) {
            const int base_f = c * Ls;
            const int base_r = SLEN - (c + 1) * Ls;
            gemm_zin<<<dim3(mtiles, 4), 512, 0, stream>>>(
                sent, embed, w_ih_f, w_ih_r, b_ih_f, b_hh_f, b_ih_r, b_hh_r,
                Z, base_f, base_r);
            fused_lstm_gemm<<<128, 512, 0, stream>>>(
                sent, embed, w_ih_f, w_ih_r, b_ih_f, b_hh_f, b_ih_r, b_hh_r,
                Z, 0, 0, mtiles,
                Z, w_hh_f, w_hh_r, H, ST, base_f, base_r, Ls, c == 0 ? 1 : 0);
        }
        emissions_k<<<1024, 256, 0, stream>>>(H, w_out, b_out, F);
        viterbi_k<<<64, 64, 0, stream>>>(F, start_t, end_t, trans, out);
    }
}

// Round 15
// 1121.254 us; speedup vs baseline: 1.1276x; 1.1276x over previous
//
#include <hip/hip_runtime.h>
#include <cstdint>
#include <cstddef>

#define SLEN 1024
#define BATCH 64
#define EDIM 256
#define HDIM 128   // hidden per direction
#define GDIM 512   // 4*HDIM
#define NTAG 4
#define VOCAB 32000

typedef float f2 __attribute__((ext_vector_type(2)));
typedef float f4 __attribute__((ext_vector_type(4)));

// ---------------------------------------------------------------------------
// ws layout (table path), floats:
//   T : [32000][1024]  gate-input table  embed@W_ih_cat^T + (b_ih+b_hh)
//   H : [S][B][256]
//   F : [S][B][4]
// Fallback (old pipelined path) if ws too small: Z0|Z1|H|F|ST as before.
//
// SESSION LEDGER (final): per-step cost of the 256KB W_hh delivery per CU:
//   R4/R11 scratch-spill (lstm_k below) 0.72 us/step  <- BEST, reproduced 4x
//   R9 L2 stream 0.82 | R7 1024thr+fence 0.87 | R5 1024thr 0.88
//   R10 half-W in LDS 0.94 | R8 B_b=2 batch reuse 1.32
// VGPR residency allocator-blocked (0-for-5 attribute/geometry attempts).
// table_k: v1 tile GEMM 360us (LDS-issue bound ~33% fp32 peak: 4 ds_read_b128
// per 64 FMA, 192 vs 64 wall-cy); v2 scalar-operand REGRESSED to ~500us
// (backend didn't scalarize W loads). This = the twice-verified R4/R11
// configuration (1122-1123 us).
// ---------------------------------------------------------------------------

__device__ __forceinline__ float sigm_f(float x) {
    return 1.0f / (1.0f + __expf(-x));
}
__device__ __forceinline__ float tanh_f(float x) {
    return 1.0f - 2.0f / (1.0f + __expf(2.0f * x));
}

template <int CTRL>
__device__ __forceinline__ float quad_perm(float x) {
    return __int_as_float(
        __builtin_amdgcn_mov_dpp(__float_as_int(x), CTRL, 0xF, 0xF, true));
}
#define QP_XOR1 0xB1    // quad_perm [1,0,3,2]
#define QP_XOR2 0x4E    // quad_perm [2,3,0,1]
#define QP_MIR8 0x141   // row_half_mirror: lane p <-> 7-p within each 8
#define QP_BC0  0x00    // quad broadcast lane 0
#define QP_BC1  0x55
#define QP_BC2  0xAA
#define QP_BC3  0xFF

// ---------------------------------------------------------------------------
// table_k (v1, verified): T[v][0:512] = embed[v]@w_ih_f^T + b_ih_f + b_hh_f
//                         T[v][512:1024] = embed[v]@w_ih_r^T + b_ih_r + b_hh_r
// 512 threads, two 256-thread teams share the A-tile; BK=32; 48KB smem.
// grid (250, 4): mt=blockIdx.x (128 vocab rows), cp=blockIdx.y (col pair).
// ---------------------------------------------------------------------------
__global__ __launch_bounds__(512) void table_k(
    const float* __restrict__ embed,
    const float* __restrict__ w_ih_f, const float* __restrict__ w_ih_r,
    const float* __restrict__ b_ih_f, const float* __restrict__ b_hh_f,
    const float* __restrict__ b_ih_r, const float* __restrict__ b_hh_r,
    float* __restrict__ T)
{
    __shared__ __align__(16) float smem[12288];   // 48 KB
    float* As = smem;                       // [32][128]
    const int t  = threadIdx.x;
    const int tm = t >> 8;
    const int tt = t & 255;
    float* Bs = smem + 4096 + tm * 4096;

    const int mt  = blockIdx.x;             // 0..249
    const int cp  = blockIdx.y;             // 0..3
    const int nt  = cp * 2 + tm;            // 0..7
    const int dir = nt >> 2;
    const float* W  = dir ? w_ih_r : w_ih_f;
    const float* bi = dir ? b_ih_r : b_ih_f;
    const float* bh = dir ? b_hh_r : b_hh_f;
    const int ncol = (nt & 3) * 128;
    const int r0   = mt * 128;

    const int sra = t & 127;
    const int qa  = t >> 7;
    const float* arow = embed + (size_t)(r0 + sra) * EDIM + qa * 8;

    const int srb = tt & 127;
    const int hb  = tt >> 7;
    const float* brow = W + (size_t)(ncol + srb) * EDIM + hb * 16;

    const int tx = tt & 15, ty = tt >> 4;

    f2 acc[8][4];
    #pragma unroll
    for (int i = 0; i < 8; ++i)
        #pragma unroll
        for (int jj = 0; jj < 4; ++jj) acc[i][jj] = (f2)(0.0f);

    for (int kt = 0; kt < 8; ++kt) {
        const int k0 = kt * 32;
        __syncthreads();
        {
            float4 v0 = *(const float4*)(arow + k0);
            float4 v1 = *(const float4*)(arow + k0 + 4);
            const int kk = qa * 8;
            As[(kk + 0) * 128 + sra] = v0.x;
            As[(kk + 1) * 128 + sra] = v0.y;
            As[(kk + 2) * 128 + sra] = v0.z;
            As[(kk + 3) * 128 + sra] = v0.w;
            As[(kk + 4) * 128 + sra] = v1.x;
            As[(kk + 5) * 128 + sra] = v1.y;
            As[(kk + 6) * 128 + sra] = v1.z;
            As[(kk + 7) * 128 + sra] = v1.w;
        }
        #pragma unroll
        for (int i = 0; i < 4; ++i) {
            float4 v = *(const float4*)(brow + k0 + i * 4);
            const int kk = hb * 16 + i * 4;
            Bs[(kk + 0) * 128 + srb] = v.x;
            Bs[(kk + 1) * 128 + srb] = v.y;
            Bs[(kk + 2) * 128 + srb] = v.z;
            Bs[(kk + 3) * 128 + srb] = v.w;
        }
        __syncthreads();

        #pragma unroll 8
        for (int k = 0; k < 32; ++k) {
            const f4 a0  = *(const f4*)&As[k * 128 + ty * 4];
            const f4 a1  = *(const f4*)&As[k * 128 + 64 + ty * 4];
            const f4 bq0 = *(const f4*)&Bs[k * 128 + tx * 4];
            const f4 bq1 = *(const f4*)&Bs[k * 128 + 64 + tx * 4];
            float av[8] = {a0.x, a0.y, a0.z, a0.w, a1.x, a1.y, a1.z, a1.w};
            f2 bv[4];
            bv[0] = __builtin_shufflevector(bq0, bq0, 0, 1);
            bv[1] = __builtin_shufflevector(bq0, bq0, 2, 3);
            bv[2] = __builtin_shufflevector(bq1, bq1, 0, 1);
            bv[3] = __builtin_shufflevector(bq1, bq1, 2, 3);
            #pragma unroll
            for (int i = 0; i < 8; ++i) {
                f2 as; as.x = av[i]; as.y = av[i];
                #pragma unroll
                for (int jj = 0; jj < 4; ++jj)
                    acc[i][jj] += as * bv[jj];   // v_pk_fma_f32
            }
        }
    }

    float bias0[4], bias1[4];
    #pragma unroll
    for (int j = 0; j < 4; ++j) {
        bias0[j] = bi[ncol + tx * 4 + j] + bh[ncol + tx * 4 + j];
        bias1[j] = bi[ncol + 64 + tx * 4 + j] + bh[ncol + 64 + tx * 4 + j];
    }

    #pragma unroll
    for (int i = 0; i < 8; ++i) {
        const int row = r0 + ((i < 4) ? (ty * 4 + i) : (64 + ty * 4 + i - 4));
        float* zp = T + (size_t)row * 1024 + dir * 512 + ncol;
        float4 o0, o1;
        o0.x = acc[i][0].x + bias0[0]; o0.y = acc[i][0].y + bias0[1];
        o0.z = acc[i][1].x + bias0[2]; o0.w = acc[i][1].y + bias0[3];
        o1.x = acc[i][2].x + bias1[0]; o1.y = acc[i][2].y + bias1[1];
        o1.z = acc[i][3].x + bias1[2]; o1.w = acc[i][3].y + bias1[3];
        *(float4*)(zp + tx * 4)      = o0;
        *(float4*)(zp + 64 + tx * 4) = o1;
    }
}

// ---------------------------------------------------------------------------
// lstm_k (R4/v12 exact, reproduced 4x at 729-737us): one block per (b,dir),
// 512 threads, full sequence. z from precomputed T via coalesced per-token
// gather with 4-step prefetch. w2 nominally pinned; the allocator spills it
// to scratch (VGPR_Count 88) and the COMPILER-SCHEDULED scratch reload is the
// fastest measured W-delivery on this toolchain (0.72 us/step, ledger above).
// Do not "improve" this loop without beating 737 us end-to-end.
// ---------------------------------------------------------------------------
__global__ __launch_bounds__(512) __attribute__((amdgpu_waves_per_eu(2, 2)))
void lstm_k(
    const float* __restrict__ T, const int* __restrict__ sent,
    const float* __restrict__ w_hh_f, const float* __restrict__ w_hh_r,
    float* __restrict__ H)
{
    __shared__ __align__(16) float sh_h[320];   // [2][160] padded 32->36
    __shared__ int sh_tok[SLEN];

    const int bid = blockIdx.x;
    const int b   = bid & 63;
    const int dir = bid >> 6;
    const int q   = threadIdx.x;     // 0..511
    const int p   = q & 7;
    const int Q   = q >> 3;          // 0..63
    const int gt  = p & 3;           // gate i,f,g,o
    const int hi  = p >> 2;          // 0: unit Q, 1: unit Q+64
    const int u   = Q + hi * 64;

    const float* Whh = dir ? w_hh_r : w_hh_f;

    // w2[pr][i]: pair pr = (unit pr&4 ? Q+64 : Q, gate pr&3), elems [16p,16p+16)
    f2 w2[8][8];
    #pragma unroll
    for (int pr = 0; pr < 8; ++pr) {
        const int uu = (pr & 4) ? (Q + 64) : Q;
        const int gg = pr & 3;
        const f2* src =
            (const f2*)(Whh + ((size_t)(gg * 128 + uu) * 128 + p * 16));
        #pragma unroll
        for (int i = 0; i < 8; ++i) w2[pr][i] = src[i];
    }
    // PIN attempt (allocator spills to scratch; scratch reload is the best
    // measured delivery — keep as-is).
    #pragma unroll
    for (int pr = 0; pr < 8; ++pr)
        #pragma unroll
        for (int i = 0; i < 8; ++i)
            asm volatile("" : "+v"(w2[pr][i]));

    // stage the token row + zero h
    sh_tok[q]       = sent[b * SLEN + q];
    sh_tok[512 + q] = sent[b * SLEN + 512 + q];
    if (q < 128) sh_h[(q >> 5) * 36 + (q & 31)] = 0.0f;
    float c = 0.0f;
    __syncthreads();

    const int zcol = dir * 512 + gt * 128 + u;
    const ptrdiff_t hstride = dir ? -16384 : 16384;
    float* hg = H + ((size_t)(dir ? (SLEN - 1) : 0) * 64 + b) * 256
              + dir * 128 + u;

    const bool k4 = (p & 4) != 0;
    const bool k2 = (p & 2) != 0;
    const bool k1 = (p & 1) != 0;
    const float gsc  = (gt == 2) ? 2.0f : 1.0f;    // tanh(x)=2*sigm(2x)-1
    const float gofs = (gt == 2) ? -1.0f : 0.0f;
    const int shr = (p >> 1) * 36 + (p & 1) * 16;
    const int shw = (u >> 5) * 36 + (u & 31);

    float zcur[4], znxt[4];
    #pragma unroll
    for (int dt = 0; dt < 4; ++dt) {
        const int s = dir ? (SLEN - 1 - dt) : dt;
        zcur[dt] = T[((size_t)sh_tok[s] << 10) + zcol];
    }

    for (int t0 = 0; t0 < SLEN; t0 += 4) {
        const bool more = (t0 + 4 < SLEN);
        if (more) {
            #pragma unroll
            for (int dt = 0; dt < 4; ++dt) {
                const int tn = t0 + 4 + dt;
                const int s = dir ? (SLEN - 1 - tn) : tn;
                znxt[dt] = T[((size_t)sh_tok[s] << 10) + zcol];
            }
        }

        #pragma unroll
        for (int dt = 0; dt < 4; ++dt) {
            // h(t) slice [16p, 16p+16): 4 conflict-free ds_read_b128
            const f4* hp = (const f4*)(sh_h + (dt & 1) * 160 + shr);
            f2 hv[8];
            #pragma unroll
            for (int i = 0; i < 4; ++i) {
                f4 v = hp[i];
                hv[2 * i]     = __builtin_shufflevector(v, v, 0, 1);
                hv[2 * i + 1] = __builtin_shufflevector(v, v, 2, 3);
            }
            // partial dots for all 8 pairs (exact work: 64 pk_fma)
            float s[8];
            #pragma unroll
            for (int pr = 0; pr < 8; ++pr) {
                f2 a = (f2)(0.0f);
                #pragma unroll
                for (int i = 0; i < 8; ++i) a += w2[pr][i] * hv[i];
                s[pr] = a.x + a.y;
            }
            // reduce-scatter over the 8-lane group: lane p ends with pair p
            float K1[4];
            #pragma unroll
            for (int j = 0; j < 4; ++j) {
                float keep = k4 ? s[j + 4] : s[j];
                float send = k4 ? s[j] : s[j + 4];
                K1[j] = keep + quad_perm<QP_MIR8>(send);
            }
            float K2[2];
            #pragma unroll
            for (int j = 0; j < 2; ++j) {
                float keep = k2 ? K1[j + 2] : K1[j];
                float send = k2 ? K1[j] : K1[j + 2];
                K2[j] = keep + quad_perm<QP_XOR2>(send);
            }
            float keep3 = k1 ? K2[1] : K2[0];
            float send3 = k1 ? K2[0] : K2[1];
            float zv = keep3 + quad_perm<QP_XOR1>(send3) + zcur[dt];

            // one activation per lane (sigmoid, or tanh when gt==2)
            float sgv = sigm_f(zv * gsc);
            float act = fmaf(sgv, gsc, gofs);

            // gather the quad's 4 gate activations
            float a_i = quad_perm<QP_BC0>(act);
            float a_f = quad_perm<QP_BC1>(act);
            float a_g = quad_perm<QP_BC2>(act);
            float a_o = quad_perm<QP_BC3>(act);
            c = a_f * c + a_i * a_g;
            float h = a_o * tanh_f(c);

            if (gt == 0) {                  // p==0 writes unit Q, p==4 -> Q+64
                sh_h[((dt + 1) & 1) * 160 + shw] = h;
                *hg = h;
            }
            hg += hstride;
            __syncthreads();
        }

        if (more) {
            #pragma unroll
            for (int dt = 0; dt < 4; ++dt) zcur[dt] = znxt[dt];
        }
    }
}

// ===========================================================================
// FALLBACK path kernels (old pipelined design), used only if ws too small.
// ===========================================================================
__device__ __forceinline__ void gemm_body(
    float* smem, int mt, int cp,
    const int* __restrict__ sent, const float* __restrict__ embed,
    const float* __restrict__ w_ih_f, const float* __restrict__ w_ih_r,
    const float* __restrict__ b_ih_f, const float* __restrict__ b_hh_f,
    const float* __restrict__ b_ih_r, const float* __restrict__ b_hh_r,
    float* __restrict__ Z, int base_f, int base_r)
{
    float* As = smem;
    const int t  = threadIdx.x;
    const int tm = t >> 8;
    const int tt = t & 255;
    float* Bs = smem + 4096 + tm * 4096;

    const int nt  = cp * 2 + tm;
    const int dir = nt >> 2;
    const float* W  = dir ? w_ih_r : w_ih_f;
    const float* bi = dir ? b_ih_r : b_ih_f;
    const float* bh = dir ? b_hh_r : b_hh_f;
    const int ncol = (nt & 3) * 128;
    const int r0   = mt * 128;

    const int sra = t & 127;
    const int qa  = t >> 7;
    const int r_loc = r0 + sra;
    const int s_loc = r_loc >> 6;
    const int b_    = r_loc & 63;
    const int s_glob = (dir ? base_r : base_f) + s_loc;
    const int tok = sent[b_ * SLEN + s_glob];
    const float* arow = embed + (size_t)tok * EDIM + qa * 8;

    const int srb = tt & 127;
    const int hb  = tt >> 7;
    const float* brow = W + (size_t)(ncol + srb) * EDIM + hb * 16;

    const int tx = tt & 15, ty = tt >> 4;

    f2 acc[8][4];
    #pragma unroll
    for (int i = 0; i < 8; ++i)
        #pragma unroll
        for (int jj = 0; jj < 4; ++jj) acc[i][jj] = (f2)(0.0f);

    for (int kt = 0; kt < 8; ++kt) {
        const int k0 = kt * 32;
        __syncthreads();
        {
            float4 v0 = *(const float4*)(arow + k0);
            float4 v1 = *(const float4*)(arow + k0 + 4);
            const int kk = qa * 8;
            As[(kk + 0) * 128 + sra] = v0.x;
            As[(kk + 1) * 128 + sra] = v0.y;
            As[(kk + 2) * 128 + sra] = v0.z;
            As[(kk + 3) * 128 + sra] = v0.w;
            As[(kk + 4) * 128 + sra] = v1.x;
            As[(kk + 5) * 128 + sra] = v1.y;
            As[(kk + 6) * 128 + sra] = v1.z;
            As[(kk + 7) * 128 + sra] = v1.w;
        }
        #pragma unroll
        for (int i = 0; i < 4; ++i) {
            float4 v = *(const float4*)(brow + k0 + i * 4);
            const int kk = hb * 16 + i * 4;
            Bs[(kk + 0) * 128 + srb] = v.x;
            Bs[(kk + 1) * 128 + srb] = v.y;
            Bs[(kk + 2) * 128 + srb] = v.z;
            Bs[(kk + 3) * 128 + srb] = v.w;
        }
        __syncthreads();

        #pragma unroll 8
        for (int k = 0; k < 32; ++k) {
            const f4 a0  = *(const f4*)&As[k * 128 + ty * 4];
            const f4 a1  = *(const f4*)&As[k * 128 + 64 + ty * 4];
            const f4 bq0 = *(const f4*)&Bs[k * 128 + tx * 4];
            const f4 bq1 = *(const f4*)&Bs[k * 128 + 64 + tx * 4];
            float av[8] = {a0.x, a0.y, a0.z, a0.w, a1.x, a1.y, a1.z, a1.w};
            f2 bv[4];
            bv[0] = __builtin_shufflevector(bq0, bq0, 0, 1);
            bv[1] = __builtin_shufflevector(bq0, bq0, 2, 3);
            bv[2] = __builtin_shufflevector(bq1, bq1, 0, 1);
            bv[3] = __builtin_shufflevector(bq1, bq1, 2, 3);
            #pragma unroll
            for (int i = 0; i < 8; ++i) {
                f2 as; as.x = av[i]; as.y = av[i];
                #pragma unroll
                for (int jj = 0; jj < 4; ++jj)
                    acc[i][jj] += as * bv[jj];
            }
        }
    }

    float bias0[4], bias1[4];
    #pragma unroll
    for (int j = 0; j < 4; ++j) {
        bias0[j] = bi[ncol + tx * 4 + j] + bh[ncol + tx * 4 + j];
        bias1[j] = bi[ncol + 64 + tx * 4 + j] + bh[ncol + 64 + tx * 4 + j];
    }

    #pragma unroll
    for (int i = 0; i < 8; ++i) {
        const int row = r0 + ((i < 4) ? (ty * 4 + i) : (64 + ty * 4 + i - 4));
        float* zp = Z + (size_t)row * 1024 + dir * 512 + ncol;
        float4 o0, o1;
        o0.x = acc[i][0].x + bias0[0]; o0.y = acc[i][0].y + bias0[1];
        o0.z = acc[i][1].x + bias0[2]; o0.w = acc[i][1].y + bias0[3];
        o1.x = acc[i][2].x + bias1[0]; o1.y = acc[i][2].y + bias1[1];
        o1.z = acc[i][3].x + bias1[2]; o1.w = acc[i][3].y + bias1[3];
        *(float4*)(zp + tx * 4)      = o0;
        *(float4*)(zp + 64 + tx * 4) = o1;
    }
}

__device__ __forceinline__ void lstm_body(
    float* smem,
    const float* __restrict__ Z, const float* __restrict__ w_hh_f,
    const float* __restrict__ w_hh_r, float* __restrict__ H,
    float* __restrict__ ST, int base_f, int base_r, int L, int first)
{
    float* sh_h = smem;

    const int bid = blockIdx.x;
    const int b   = bid & 63;
    const int dir = bid >> 6;
    const int q   = threadIdx.x;
    const int p   = q & 7;
    const int Q   = q >> 3;
    const int gt  = p & 3;
    const int hi  = p >> 2;
    const int u   = Q + hi * 64;

    const float* Whh = dir ? w_hh_r : w_hh_f;

    f2 w2[8][8];
    #pragma unroll
    for (int pr = 0; pr < 8; ++pr) {
        const int uu = (pr & 4) ? (Q + 64) : Q;
        const int gg = pr & 3;
        const f2* src =
            (const f2*)(Whh + ((size_t)(gg * 128 + uu) * 128 + p * 16));
        #pragma unroll
        for (int i = 0; i < 8; ++i) w2[pr][i] = src[i];
    }

    float* stp = ST + (size_t)(dir * 64 + b) * 256;
    if (q < 128)
        sh_h[(q >> 5) * 36 + (q & 31)] = first ? 0.0f : stp[q];
    float c = first ? 0.0f : stp[128 + u];

    const ptrdiff_t zstride = dir ? -65536 : 65536;
    const float* zp0 = Z + (size_t)b * 1024 + dir * 512
                     + (dir ? (size_t)(L - 1) * 65536 : 0) + gt * 128 + u;
    const ptrdiff_t hstride = dir ? -16384 : 16384;
    float* hg = H + ((size_t)(dir ? (base_r + L - 1) : base_f) * 64 + b) * 256
              + dir * 128 + u;

    const bool k4 = (p & 4) != 0;
    const bool k2 = (p & 2) != 0;
    const bool k1 = (p & 1) != 0;
    const float gsc  = (gt == 2) ? 2.0f : 1.0f;
    const float gofs = (gt == 2) ? -1.0f : 0.0f;
    const int shr = (p >> 1) * 36 + (p & 1) * 16;
    const int shw = (u >> 5) * 36 + (u & 31);

    float zcur[4], znxt[4];
    {
        const float* zp = zp0;
        #pragma unroll
        for (int dt = 0; dt < 4; ++dt) { zcur[dt] = *zp; zp += zstride; }
    }
    __syncthreads();

    float hlast = 0.0f;

    for (int t0 = 0; t0 < L; t0 += 4) {
        const bool more = (t0 + 4 < L);
        if (more) {
            const float* zp = zp0 + (ptrdiff_t)(t0 + 4) * zstride;
            #pragma unroll
            for (int dt = 0; dt < 4; ++dt) { znxt[dt] = *zp; zp += zstride; }
        }

        #pragma unroll
        for (int dt = 0; dt < 4; ++dt) {
            const f4* hp = (const f4*)(sh_h + (dt & 1) * 160 + shr);
            f2 hv[8];
            #pragma unroll
            for (int i = 0; i < 4; ++i) {
                f4 v = hp[i];
                hv[2 * i]     = __builtin_shufflevector(v, v, 0, 1);
                hv[2 * i + 1] = __builtin_shufflevector(v, v, 2, 3);
            }
            float s[8];
            #pragma unroll
            for (int pr = 0; pr < 8; ++pr) {
                f2 a = (f2)(0.0f);
                #pragma unroll
                for (int i = 0; i < 8; ++i) a += w2[pr][i] * hv[i];
                s[pr] = a.x + a.y;
            }
            float K1[4];
            #pragma unroll
            for (int j = 0; j < 4; ++j) {
                float keep = k4 ? s[j + 4] : s[j];
                float send = k4 ? s[j] : s[j + 4];
                K1[j] = keep + quad_perm<QP_MIR8>(send);
            }
            float K2[2];
            #pragma unroll
            for (int j = 0; j < 2; ++j) {
                float keep = k2 ? K1[j + 2] : K1[j];
                float send = k2 ? K1[j] : K1[j + 2];
                K2[j] = keep + quad_perm<QP_XOR2>(send);
            }
            float keep3 = k1 ? K2[1] : K2[0];
            float send3 = k1 ? K2[0] : K2[1];
            float zv = keep3 + quad_perm<QP_XOR1>(send3) + zcur[dt];

            float sgv = sigm_f(zv * gsc);
            float act = fmaf(sgv, gsc, gofs);

            float a_i = quad_perm<QP_BC0>(act);
            float a_f = quad_perm<QP_BC1>(act);
            float a_g = quad_perm<QP_BC2>(act);
            float a_o = quad_perm<QP_BC3>(act);
            c = a_f * c + a_i * a_g;
            float h = a_o * tanh_f(c);
            hlast = h;

            if (gt == 0) {
                sh_h[((dt + 1) & 1) * 160 + shw] = h;
                *hg = h;
            }
            hg += hstride;
            __syncthreads();
        }

        if (more) {
            #pragma unroll
            for (int dt = 0; dt < 4; ++dt) zcur[dt] = znxt[dt];
        }
    }

    if (gt == 0) {
        stp[u] = hlast;
        stp[128 + u] = c;
    }
}

__global__ __launch_bounds__(512) void fused_lstm_gemm(
    const int* __restrict__ sent, const float* __restrict__ embed,
    const float* __restrict__ w_ih_f, const float* __restrict__ w_ih_r,
    const float* __restrict__ b_ih_f, const float* __restrict__ b_hh_f,
    const float* __restrict__ b_ih_r, const float* __restrict__ b_hh_r,
    float* __restrict__ Zw, int gbase_f, int gbase_r, int mtiles,
    const float* __restrict__ Zr, const float* __restrict__ w_hh_f,
    const float* __restrict__ w_hh_r, float* __restrict__ H,
    float* __restrict__ ST, int lbase_f, int lbase_r, int L, int first)
{
    __shared__ __align__(16) float smem[12288];

    if (blockIdx.x < 128) {
        lstm_body(smem, Zr, w_hh_f, w_hh_r, H, ST, lbase_f, lbase_r, L, first);
    } else {
        const int g  = blockIdx.x - 128;
        const int mt = g % mtiles;
        const int cp = g / mtiles;
        gemm_body(smem, mt, cp, sent, embed, w_ih_f, w_ih_r,
                  b_ih_f, b_hh_f, b_ih_r, b_hh_r, Zw, gbase_f, gbase_r);
    }
}

__global__ __launch_bounds__(512) void gemm_zin(
    const int* __restrict__ sent, const float* __restrict__ embed,
    const float* __restrict__ w_ih_f, const float* __restrict__ w_ih_r,
    const float* __restrict__ b_ih_f, const float* __restrict__ b_hh_f,
    const float* __restrict__ b_ih_r, const float* __restrict__ b_hh_r,
    float* __restrict__ Z, int base_f, int base_r)
{
    __shared__ __align__(16) float smem[12288];
    gemm_body(smem, blockIdx.x, blockIdx.y, sent, embed, w_ih_f, w_ih_r,
              b_ih_f, b_hh_f, b_ih_r, b_hh_r, Z, base_f, base_r);
}

// ---------------------------------------------------------------------------
// Kernel 3: emissions  F[r][t] = H[r] . w_out[t] + b_out[t]
// ---------------------------------------------------------------------------
__global__ __launch_bounds__(256) void emissions_k(
    const float* __restrict__ H, const float* __restrict__ w_out,
    const float* __restrict__ b_out, float* __restrict__ F)
{
    const int gid = blockIdx.x * 256 + threadIdx.x;
    const int r   = gid >> 2;
    const int tg  = gid & 3;
    const float4* h4 = (const float4*)(H + (size_t)r * 256);
    const float4* w4 = (const float4*)(w_out + (size_t)tg * 256);
    float a0 = 0.f, a1 = 0.f, a2 = 0.f, a3 = 0.f;
    #pragma unroll 8
    for (int k = 0; k < 64; ++k) {
        float4 h = h4[k], w = w4[k];
        a0 = fmaf(h.x, w.x, a0); a1 = fmaf(h.y, w.y, a1);
        a2 = fmaf(h.z, w.z, a2); a3 = fmaf(h.w, w.w, a3);
    }
    F[gid] = ((a0 + a1) + (a2 + a3)) + b_out[tg];
}

// ---------------------------------------------------------------------------
// Kernel 4: Viterbi. One block (1 wave) per batch.
// ---------------------------------------------------------------------------
__device__ __forceinline__ unsigned compose_map(unsigned a, unsigned b) {
    unsigned r = 0;
    #pragma unroll
    for (int jj = 0; jj < 4; ++jj) {
        unsigned bj = (b >> (jj * 8)) & 3u;
        unsigned aj = (a >> (bj * 8)) & 3u;
        r |= aj << (jj * 8);
    }
    return r;
}

__global__ __launch_bounds__(64) void viterbi_k(
    const float* __restrict__ F, const float* __restrict__ start_t,
    const float* __restrict__ end_t, const float* __restrict__ trans,
    int* __restrict__ out)
{
    const int b    = blockIdx.x;
    const int lane = threadIdx.x;
    __shared__ __align__(16) float sfeat[SLEN][NTAG];
    __shared__ unsigned sbp[SLEN];

    #pragma unroll
    for (int i = 0; i < 16; ++i) {
        int s = i * 64 + lane;
        ((float4*)sfeat)[s] = *(const float4*)(F + ((size_t)s * BATCH + b) * NTAG);
    }
    __syncthreads();

    const int cur = lane & 3;
    float tr0 = trans[0 * 4 + cur], tr1 = trans[1 * 4 + cur];
    float tr2 = trans[2 * 4 + cur], tr3 = trans[3 * 4 + cur];
    float sc = start_t[cur] + sfeat[0][cur];

    for (int s = 1; s < SLEN; ++s) {
        float ft = sfeat[s][cur];
        float s0 = __shfl(sc, 0), s1 = __shfl(sc, 1);
        float s2 = __shfl(sc, 2), s3 = __shfl(sc, 3);
        float c0 = s0 + tr0, c1 = s1 + tr1, c2 = s2 + tr2, c3 = s3 + tr3;
        float best = c0; int arg = 0;
        if (c1 > best) { best = c1; arg = 1; }
        if (c2 > best) { best = c2; arg = 2; }
        if (c3 > best) { best = c3; arg = 3; }
        sc = best + ft;
        unsigned bp = (unsigned)arg;
        unsigned b0 = __shfl(bp, 0), b1 = __shfl(bp, 1);
        unsigned b2 = __shfl(bp, 2), b3 = __shfl(bp, 3);
        if (lane == 0) sbp[s] = b0 | (b1 << 8) | (b2 << 16) | (b3 << 24);
    }
    sc += end_t[cur];
    float f0 = __shfl(sc, 0), f1 = __shfl(sc, 1);
    float f2v = __shfl(sc, 2), f3 = __shfl(sc, 3);
    int last = 0; float bb = f0;
    if (f1 > bb)  { bb = f1;  last = 1; }
    if (f2v > bb) { bb = f2v; last = 2; }
    if (f3 > bb)  { bb = f3;  last = 3; }
    __syncthreads();

    unsigned m[16];
    #pragma unroll
    for (int k = 0; k < 16; ++k) {
        int s = lane * 16 + k;
        m[k] = (s >= 1) ? sbp[s] : 0x03020100u;
    }
    unsigned G = m[15];
    #pragma unroll
    for (int k = 14; k >= 0; --k) G = compose_map(m[k], G);
    unsigned R = G;
    #pragma unroll
    for (int d = 1; d < 64; d <<= 1) {
        unsigned oo = __shfl_down(R, d);
        if (lane + d < 64) R = compose_map(R, oo);
    }
    unsigned P = __shfl_down(R, 1);
    if (lane == 63) P = 0x03020100u;

    int tcur = (int)((P >> (last * 8)) & 3u);
    int* ob = out + b * SLEN + lane * 16;
    ob[15] = tcur;
    #pragma unroll
    for (int k = 15; k >= 1; --k) {
        tcur = (int)((m[k] >> (tcur * 8)) & 3u);
        ob[k - 1] = tcur;
    }
}

// ---------------------------------------------------------------------------
extern "C" void kernel_launch(void* const* d_in, const int* in_sizes, int n_in,
                              void* d_out, int out_size, void* d_ws, size_t ws_size,
                              hipStream_t stream)
{
    const int*   sent    = (const int*)d_in[0];
    const float* embed   = (const float*)d_in[1];
    const float* w_ih_f  = (const float*)d_in[2];
    const float* w_hh_f  = (const float*)d_in[3];
    const float* b_ih_f  = (const float*)d_in[4];
    const float* b_hh_f  = (const float*)d_in[5];
    const float* w_ih_r  = (const float*)d_in[6];
    const float* w_hh_r  = (const float*)d_in[7];
    const float* b_ih_r  = (const float*)d_in[8];
    const float* b_hh_r  = (const float*)d_in[9];
    const float* w_out   = (const float*)d_in[10];
    const float* b_out   = (const float*)d_in[11];
    const float* start_t = (const float*)d_in[12];
    const float* end_t   = (const float*)d_in[13];
    const float* trans   = (const float*)d_in[14];
    int* out = (int*)d_out;

    const size_t H_FLOATS  = (size_t)SLEN * BATCH * 256;   // 16777216
    const size_t F_FLOATS  = (size_t)SLEN * BATCH * NTAG;  //   262144
    const size_t T_FLOATS  = (size_t)VOCAB * 1024;         // 32768000
    const size_t ST_FLOATS = (size_t)2 * BATCH * 256;

    const size_t table_need = (T_FLOATS + H_FLOATS + F_FLOATS) * sizeof(float);

    if (ws_size >= table_need) {
        // -------- table path --------
        float* T = (float*)d_ws;
        float* H = T + T_FLOATS;
        float* F = H + H_FLOATS;

        table_k<<<dim3(250, 4), 512, 0, stream>>>(
            embed, w_ih_f, w_ih_r, b_ih_f, b_hh_f, b_ih_r, b_hh_r, T);
        lstm_k<<<128, 512, 0, stream>>>(T, sent, w_hh_f, w_hh_r, H);
        emissions_k<<<1024, 256, 0, stream>>>(H, w_out, b_out, F);
        viterbi_k<<<64, 64, 0, stream>>>(F, start_t, end_t, trans, out);
        return;
    }

    // -------- fallback: old pipelined path --------
    const size_t FIXED = H_FLOATS + F_FLOATS + ST_FLOATS;
    int L = 0;
    for (int cand = 256; cand >= 32; cand >>= 1) {
        size_t need = ((size_t)2 * cand * BATCH * 1024 + FIXED) * sizeof(float);
        if (need <= ws_size) { L = cand; break; }
    }

    if (L > 0) {
        const int nch = SLEN / L;
        const int mtiles = (L * BATCH) / 128;
        float* Z0 = (float*)d_ws;
        float* Z1 = Z0 + (size_t)L * BATCH * 1024;
        float* H  = Z1 + (size_t)L * BATCH * 1024;
        float* F  = H + H_FLOATS;
        float* ST = F + F_FLOATS;
        float* Zb[2] = {Z0, Z1};

        gemm_zin<<<dim3(mtiles, 4), 512, 0, stream>>>(
            sent, embed, w_ih_f, w_ih_r, b_ih_f, b_hh_f, b_ih_r, b_hh_r,
            Zb[0], 0, SLEN - L);

        for (int c = 0; c < nch; ++c) {
            const int lbase_f = c * L;
            const int lbase_r = SLEN - (c + 1) * L;
            const int hasg = (c + 1 < nch);
            const int gbase_f = (c + 1) * L;
            const int gbase_r = SLEN - (c + 2) * L;
            const int grid = hasg ? (128 + mtiles * 4) : 128;
            fused_lstm_gemm<<<grid, 512, 0, stream>>>(
                sent, embed, w_ih_f, w_ih_r, b_ih_f, b_hh_f, b_ih_r, b_hh_r,
                Zb[(c + 1) & 1], hasg ? gbase_f : 0, hasg ? gbase_r : 0, mtiles,
                Zb[c & 1], w_hh_f, w_hh_r, H, ST, lbase_f, lbase_r, L,
                c == 0 ? 1 : 0);
        }

        emissions_k<<<1024, 256, 0, stream>>>(H, w_out, b_out, F);
        viterbi_k<<<64, 64, 0, stream>>>(F, start_t, end_t, trans, out);
    } else {
        int Ls = SLEN;
        while (Ls > 32) {
            size_t need = ((size_t)Ls * BATCH * 1024 + FIXED) * sizeof(float);
            if (need <= ws_size) break;
            Ls >>= 1;
        }
        const int nch = SLEN / Ls;
        const int mtiles = (Ls * BATCH) / 128;
        float* Z  = (float*)d_ws;
        float* H  = Z + (size_t)Ls * BATCH * 1024;
        float* F  = H + H_FLOATS;
        float* ST = F + F_FLOATS;

        for (int c = 0; c < nch; ++c) {
            const int base_f = c * Ls;
            const int base_r = SLEN - (c + 1) * Ls;
            gemm_zin<<<dim3(mtiles, 4), 512, 0, stream>>>(
                sent, embed, w_ih_f, w_ih_r, b_ih_f, b_hh_f, b_ih_r, b_hh_r,
                Z, base_f, base_r);
            fused_lstm_gemm<<<128, 512, 0, stream>>>(
                sent, embed, w_ih_f, w_ih_r, b_ih_f, b_hh_f, b_ih_r, b_hh_r,
                Z, 0, 0, mtiles,
                Z, w_hh_f, w_hh_r, H, ST, base_f, base_r, Ls, c == 0 ? 1 : 0);
        }
        emissions_k<<<1024, 256, 0, stream>>>(H, w_out, b_out, F);
        viterbi_k<<<64, 64, 0, stream>>>(F, start_t, end_t, trans, out);
    }
}